// Round 14
// baseline (30.807 us; speedup 1.0000x reference)
//
#include <hip/hip_runtime.h>
#include <math.h>

#define LMAX  50
#define NWAVE 2048     // 512 blocks x 4 waves; each wave: elements wid, wid+2048

typedef short bf16x8 __attribute__((ext_vector_type(8)));
typedef float f32x4  __attribute__((ext_vector_type(4)));
union bfu { bf16x8 v; unsigned u[4]; };

__device__ __forceinline__ unsigned cvt_pk(float lo, float hi) {
    unsigned r;
    asm("v_cvt_pk_bf16_f32 %0, %1, %2" : "=v"(r) : "v"(lo), "v"(hi));
    return r;
}
__device__ __forceinline__ bf16x8 cvt8f(float4 a, float4 b) {
    bfu r;
    r.u[0] = cvt_pk(a.x, a.y); r.u[1] = cvt_pk(a.z, a.w);
    r.u[2] = cvt_pk(b.x, b.y); r.u[3] = cvt_pk(b.z, b.w);
    return r.v;
}
__device__ __forceinline__ float bf2f(short s) {
    union { unsigned u; float f; } v; v.u = ((unsigned)(unsigned short)s) << 16;
    return v.f;
}

// One 16-neighbor tile: layer1 -> LDS transpose -> swapped layer2 -> logits ->
// online softmax -> weighted partials. (R13's verified compute path.)
__device__ __forceinline__ void tile_compute(
    int t, int len, bf16x8 a0, bf16x8 a1,
    const f32x4 (&hn)[4],
    const bf16x8 (&w1f)[4][4], const bf16x8 (&w2f)[2][4],
    const f32x4 (&b2r)[4], const f32x4 (&w3r)[4],
    unsigned short* __restrict__ hw, int l15, int g,
    float& m, float& ssum, float (&accW)[16])
{
    const int g8 = g * 8;

    // ---- layer 1 (neighbor half), K=64 on top of hn ----
    f32x4 acc[4];
    #pragma unroll
    for (int nt = 0; nt < 4; ++nt) acc[nt] = hn[nt];
    #pragma unroll
    for (int nt = 0; nt < 4; ++nt)
        acc[nt] = __builtin_amdgcn_mfma_f32_16x16x32_bf16(a0, w1f[0][nt], acc[nt], 0, 0, 0);
    #pragma unroll
    for (int nt = 0; nt < 4; ++nt)
        acc[nt] = __builtin_amdgcn_mfma_f32_16x16x32_bf16(a1, w1f[1][nt], acc[nt], 0, 0, 0);

    // relu -> bf16 -> per-wave LDS transpose (C: row g*4+reg, col nt*16+l15)
    #pragma unroll
    for (int nt = 0; nt < 4; ++nt) {
        unsigned p0 = cvt_pk(fmaxf(acc[nt][0], 0.f), fmaxf(acc[nt][1], 0.f));
        unsigned p1 = cvt_pk(fmaxf(acc[nt][2], 0.f), fmaxf(acc[nt][3], 0.f));
        hw[(g * 4 + 0) * 72 + nt * 16 + l15] = (unsigned short)p0;
        hw[(g * 4 + 1) * 72 + nt * 16 + l15] = (unsigned short)(p0 >> 16);
        hw[(g * 4 + 2) * 72 + nt * 16 + l15] = (unsigned short)p1;
        hw[(g * 4 + 3) * 72 + nt * 16 + l15] = (unsigned short)(p1 >> 16);
    }
    bf16x8 h0 = *(const bf16x8*)&hw[l15 * 72 + g8];        // H1[nbr=l15][n1=g8+i]
    bf16x8 h1 = *(const bf16x8*)&hw[l15 * 72 + 32 + g8];

    // ---- layer 2 SWAPPED: D2 = W2^T @ H1^T (col = neighbor = l15) ----
    f32x4 c2[4];
    #pragma unroll
    for (int nt = 0; nt < 4; ++nt) c2[nt] = b2r[nt];
    #pragma unroll
    for (int nt = 0; nt < 4; ++nt)
        c2[nt] = __builtin_amdgcn_mfma_f32_16x16x32_bf16(w2f[0][nt], h0, c2[nt], 0, 0, 0);
    #pragma unroll
    for (int nt = 0; nt < 4; ++nt)
        c2[nt] = __builtin_amdgcn_mfma_f32_16x16x32_bf16(w2f[1][nt], h1, c2[nt], 0, 0, 0);

    // ---- layer 3: per-lane VALU sum over n2, then reduce over g ----
    float ls = 0.f;
    #pragma unroll
    for (int nt = 0; nt < 4; ++nt) {
        ls = fmaf(fmaxf(c2[nt][0], 0.f), w3r[nt][0], ls);
        ls = fmaf(fmaxf(c2[nt][1], 0.f), w3r[nt][1], ls);
        ls = fmaf(fmaxf(c2[nt][2], 0.f), w3r[nt][2], ls);
        ls = fmaf(fmaxf(c2[nt][3], 0.f), w3r[nt][3], ls);
    }
    ls += __shfl_xor(ls, 16);
    ls += __shfl_xor(ls, 32);              // logit[nbr=l15], replicated over g

    const int rabs = t * 16 + l15;
    const float lgv = (rabs < len) ? ls : -INFINITY;

    float tm = fmaxf(lgv, __shfl_xor(lgv, 1));
    tm = fmaxf(tm, __shfl_xor(tm, 2));
    tm = fmaxf(tm, __shfl_xor(tm, 4));
    tm = fmaxf(tm, __shfl_xor(tm, 8));
    if (tm > m) {                          // wave-uniform branch
        const float sc = __expf(m - tm);   // first tile: exp(-inf)=0
        ssum *= sc;
        #pragma unroll
        for (int i = 0; i < 16; ++i) accW[i] *= sc;
        m = tm;
    }
    const float er = __expf(lgv - m);      // this lane's row weight (0 if masked)
    ssum += er;
    #pragma unroll
    for (int i = 0; i < 8; ++i) {
        accW[i]     = fmaf(er, bf2f(a0[i]), accW[i]);
        accW[8 + i] = fmaf(er, bf2f(a1[i]), accW[8 + i]);
    }
}

__device__ __forceinline__ void finalize_elem(
    float (&accW)[16], float ssum, float* __restrict__ out,
    int b, int l15, int g)
{
    #pragma unroll
    for (int i = 0; i < 16; ++i) {
        accW[i] += __shfl_xor(accW[i], 1);
        accW[i] += __shfl_xor(accW[i], 2);
        accW[i] += __shfl_xor(accW[i], 4);
        accW[i] += __shfl_xor(accW[i], 8);
    }
    float ss = ssum;
    ss += __shfl_xor(ss, 1);
    ss += __shfl_xor(ss, 2);
    ss += __shfl_xor(ss, 4);
    ss += __shfl_xor(ss, 8);
    const float inv = 1.f / ss;
    const int g8 = g * 8;
    if (l15 == 0) {
        float4 o0 = make_float4(accW[0]  * inv, accW[1]  * inv, accW[2]  * inv, accW[3]  * inv);
        float4 o1 = make_float4(accW[4]  * inv, accW[5]  * inv, accW[6]  * inv, accW[7]  * inv);
        float4 o2 = make_float4(accW[8]  * inv, accW[9]  * inv, accW[10] * inv, accW[11] * inv);
        float4 o3 = make_float4(accW[12] * inv, accW[13] * inv, accW[14] * inv, accW[15] * inv);
        *(float4*)(out + b * 64 +      g8)     = o0;
        *(float4*)(out + b * 64 +      g8 + 4) = o1;
        *(float4*)(out + b * 64 + 32 + g8)     = o2;
        *(float4*)(out + b * 64 + 32 + g8 + 4) = o3;
    }
}

// Grid is 512 blocks = 2 blocks/CU (grid-limited residency) -> VGPR up to 256
// is free; exploit it with ALL-upfront gather buffers (R9's idea, unstarved).
__global__ __launch_bounds__(256, 2) void graphrec_k(
    const float* __restrict__ u_table, const float* __restrict__ i_table,
    const float* __restrict__ W1, const float* __restrict__ b1,
    const float* __restrict__ W2, const float* __restrict__ b2,
    const float* __restrict__ W3, const float* __restrict__ b3,
    const int* __restrict__ nodes, const int* __restrict__ neighbors,
    const int* __restrict__ lengths, float* __restrict__ out)
{
    __shared__ __attribute__((aligned(16))) short WL[24][64][8];            // 24.5 KB
    __shared__ __attribute__((aligned(16))) unsigned short Hs[4][16 * 72];  //  9.2 KB

    const int tid  = threadIdx.x;
    const int w    = tid >> 6, lane = tid & 63;
    const int l15  = lane & 15, g = lane >> 4, g8 = g * 8;

    // ---- element front-matter FIRST: len->idx and nd->u chains go airborne
    //      and their latency rides under weight staging + barrier ----
    const int wid = blockIdx.x * 4 + w;
    const int b0  = wid, b1e = wid + NWAVE;
    const int len0 = lengths[b0], len1 = lengths[b1e];
    const int nd0  = nodes[b0],   nd1  = nodes[b1e];
    const int nt0  = (len0 + 15) >> 4, nt1 = (len1 + 15) >> 4;

    int idx0[4], idx1[4];
    #pragma unroll
    for (int t = 0; t < 4; ++t) {
        int r0 = t * 16 + l15; if (r0 >= len0) r0 = len0 - 1;
        idx0[t] = (t < nt0) ? neighbors[b0 * LMAX + r0] : 0;
        int r1 = t * 16 + l15; if (r1 >= len1) r1 = len1 - 1;
        idx1[t] = (t < nt1) ? neighbors[b1e * LMAX + r1] : 0;
    }
    const float* up0 = u_table + (size_t)nd0 * 64 + g8;
    const float* up1 = u_table + (size_t)nd1 * 64 + g8;
    float4 U00 = *(const float4*)(up0);
    float4 U01 = *(const float4*)(up0 + 4);
    float4 U02 = *(const float4*)(up0 + 32);
    float4 U03 = *(const float4*)(up0 + 36);
    float4 U10 = *(const float4*)(up1);
    float4 U11 = *(const float4*)(up1 + 4);
    float4 U12 = *(const float4*)(up1 + 32);
    float4 U13 = *(const float4*)(up1 + 36);

    // ---- stage weights as frags: lane(l15,g) holds M[ks*32+g8+i][nt*16+l15].
    //      Serves as B-frag for M (layer 1) and A-frag for M^T (layer 2). ----
    for (int f = w; f < 24; f += 4) {
        const float* Ws = (f < 16) ? W1 : W2;
        const int    fi = (f < 16) ? f : f - 16;
        const int    ks = fi >> 2, nt = fi & 3;
        const float* p  = Ws + (ks * 32 + g8) * 64 + nt * 16 + l15;
        bfu r;
        r.u[0] = cvt_pk(p[0 * 64], p[1 * 64]);
        r.u[1] = cvt_pk(p[2 * 64], p[3 * 64]);
        r.u[2] = cvt_pk(p[4 * 64], p[5 * 64]);
        r.u[3] = cvt_pk(p[6 * 64], p[7 * 64]);
        *(bf16x8*)&WL[f][lane][0] = r.v;
    }
    __syncthreads();

    bf16x8 w1f[4][4], w2f[2][4];
    #pragma unroll
    for (int ks = 0; ks < 4; ++ks)
        #pragma unroll
        for (int nt = 0; nt < 4; ++nt)
            w1f[ks][nt] = *(const bf16x8*)&WL[ks * 4 + nt][lane][0];
    #pragma unroll
    for (int ks = 0; ks < 2; ++ks)
        #pragma unroll
        for (int nt = 0; nt < 4; ++nt)
            w2f[ks][nt] = *(const bf16x8*)&WL[16 + ks * 4 + nt][lane][0];

    float b1v[4];
    f32x4 b2r[4], w3r[4];
    #pragma unroll
    for (int nt = 0; nt < 4; ++nt) {
        b1v[nt] = b1[nt * 16 + l15];
        b2r[nt] = *(const f32x4*)(b2 + nt * 16 + 4 * g);
        w3r[nt] = *(const f32x4*)(W3 + nt * 16 + 4 * g);
    }
    // b3 shifts all logits equally -> softmax-invariant, skip.

    // ---- ALL of element 0's gathers upfront (4 KB/wave in flight) ----
    float4 LA0[4][4], LA1[4][4];
    #define ISSUE0(t) if ((t) < nt0) { \
        const float* xp = i_table + (size_t)idx0[t] * 64 + g8; \
        LA0[t][0] = *(const float4*)(xp); \
        LA0[t][1] = *(const float4*)(xp + 4); \
        LA0[t][2] = *(const float4*)(xp + 32); \
        LA0[t][3] = *(const float4*)(xp + 36); \
    }
    #define ISSUE1(t) if ((t) < nt1) { \
        const float* xp = i_table + (size_t)idx1[t] * 64 + g8; \
        LA1[t][0] = *(const float4*)(xp); \
        LA1[t][1] = *(const float4*)(xp + 4); \
        LA1[t][2] = *(const float4*)(xp + 32); \
        LA1[t][3] = *(const float4*)(xp + 36); \
    }
    ISSUE0(0) ISSUE0(1) ISSUE0(2) ISSUE0(3)

    // ---- node half of layer 1, elem 0 ----
    bf16x8 ax0 = cvt8f(U00, U01), ax1 = cvt8f(U02, U03);
    f32x4 hn0[4];
    #pragma unroll
    for (int nt = 0; nt < 4; ++nt)
        hn0[nt] = (f32x4){b1v[nt], b1v[nt], b1v[nt], b1v[nt]};
    #pragma unroll
    for (int nt = 0; nt < 4; ++nt)
        hn0[nt] = __builtin_amdgcn_mfma_f32_16x16x32_bf16(ax0, w1f[2][nt], hn0[nt], 0, 0, 0);
    #pragma unroll
    for (int nt = 0; nt < 4; ++nt)
        hn0[nt] = __builtin_amdgcn_mfma_f32_16x16x32_bf16(ax1, w1f[3][nt], hn0[nt], 0, 0, 0);

    unsigned short* hw = &Hs[w][0];

    // ---- element 0 tiles; elem 1's gathers issue progressively underneath ----
    float m0 = -INFINITY, ss0 = 0.f;
    float accW0[16];
    #pragma unroll
    for (int i = 0; i < 16; ++i) accW0[i] = 0.f;

    #pragma unroll
    for (int t = 0; t < 4; ++t) {
        if (t < nt0) {
            bf16x8 a0 = cvt8f(LA0[t][0], LA0[t][1]);
            bf16x8 a1 = cvt8f(LA0[t][2], LA0[t][3]);
            ISSUE1(t)      // elem-1 tile-t gather rides under this tile's compute
            tile_compute(t, len0, a0, a1, hn0, w1f, w2f, b2r, w3r,
                         hw, l15, g, m0, ss0, accW0);
        } else {
            ISSUE1(t)      // still issue remaining elem-1 gathers
        }
    }
    finalize_elem(accW0, ss0, out, b0, l15, g);

    // ---- element 1 (gathers already in flight / landed) ----
    bf16x8 bx0 = cvt8f(U10, U11), bx1 = cvt8f(U12, U13);
    f32x4 hn1[4];
    #pragma unroll
    for (int nt = 0; nt < 4; ++nt)
        hn1[nt] = (f32x4){b1v[nt], b1v[nt], b1v[nt], b1v[nt]};
    #pragma unroll
    for (int nt = 0; nt < 4; ++nt)
        hn1[nt] = __builtin_amdgcn_mfma_f32_16x16x32_bf16(bx0, w1f[2][nt], hn1[nt], 0, 0, 0);
    #pragma unroll
    for (int nt = 0; nt < 4; ++nt)
        hn1[nt] = __builtin_amdgcn_mfma_f32_16x16x32_bf16(bx1, w1f[3][nt], hn1[nt], 0, 0, 0);

    float m1 = -INFINITY, ss1 = 0.f;
    float accW1[16];
    #pragma unroll
    for (int i = 0; i < 16; ++i) accW1[i] = 0.f;

    #pragma unroll
    for (int t = 0; t < 4; ++t) {
        if (t < nt1) {
            bf16x8 a0 = cvt8f(LA1[t][0], LA1[t][1]);
            bf16x8 a1 = cvt8f(LA1[t][2], LA1[t][3]);
            tile_compute(t, len1, a0, a1, hn1, w1f, w2f, b2r, w3r,
                         hw, l15, g, m1, ss1, accW1);
        }
    }
    finalize_elem(accW1, ss1, out, b1e, l15, g);
    #undef ISSUE0
    #undef ISSUE1
}

extern "C" void kernel_launch(void* const* d_in, const int* in_sizes, int n_in,
                              void* d_out, int out_size, void* d_ws, size_t ws_size,
                              hipStream_t stream) {
    const float* u_table   = (const float*)d_in[0];
    const float* b1        = (const float*)d_in[3];
    const float* i_table   = (const float*)d_in[1];
    const float* W1        = (const float*)d_in[2];
    const float* W2        = (const float*)d_in[4];
    const float* b2        = (const float*)d_in[5];
    const float* W3        = (const float*)d_in[6];
    const float* b3        = (const float*)d_in[7];
    const int*   nodes     = (const int*)d_in[8];
    const int*   neighbors = (const int*)d_in[9];
    const int*   lengths   = (const int*)d_in[10];
    float* out = (float*)d_out;

    graphrec_k<<<dim3(NWAVE / 4), dim3(256), 0, stream>>>(
        u_table, i_table, W1, b1, W2, b2, W3, b3, nodes, neighbors, lengths, out);
}

// Round 15
// 26.639 us; speedup vs baseline: 1.1565x; 1.1565x over previous
//
#include <hip/hip_runtime.h>
#include <math.h>

#define LMAX  50
#define NWAVE 2048     // 512 blocks x 4 waves; each wave: elements wid, wid+2048

typedef short bf16x8 __attribute__((ext_vector_type(8)));
typedef float f32x4  __attribute__((ext_vector_type(4)));
union bfu { bf16x8 v; unsigned u[4]; };

__device__ __forceinline__ unsigned cvt_pk(float lo, float hi) {
    unsigned r;
    asm("v_cvt_pk_bf16_f32 %0, %1, %2" : "=v"(r) : "v"(lo), "v"(hi));
    return r;
}
__device__ __forceinline__ bf16x8 cvt8f(float4 a, float4 b) {
    bfu r;
    r.u[0] = cvt_pk(a.x, a.y); r.u[1] = cvt_pk(a.z, a.w);
    r.u[2] = cvt_pk(b.x, b.y); r.u[3] = cvt_pk(b.z, b.w);
    return r.v;
}
__device__ __forceinline__ float bf2f(short s) {
    union { unsigned u; float f; } v; v.u = ((unsigned)(unsigned short)s) << 16;
    return v.f;
}

// Two 16-row tiles (t0, t0+1) traverse ONE chain: independent MFMA chains
// (2x ILP), shared LDS round trip, single softmax step per pair.
__device__ __forceinline__ void pair_compute(
    int t0, int len, bool vB,
    bf16x8 a0A, bf16x8 a1A, bf16x8 a0B, bf16x8 a1B,
    const f32x4 (&hn)[4],
    const bf16x8 (&w1f)[4][4], const bf16x8 (&w2f)[2][4],
    const f32x4 (&b2r)[4], const f32x4 (&w3r)[4],
    unsigned short* __restrict__ hw, int l15, int g,
    float& m, float& ssum, float (&accW)[16])
{
    const int g8 = g * 8;
    unsigned short* hwA = hw;
    unsigned short* hwB = hw + 16 * 72;

    // ---- layer 1, both tiles (independent chains) ----
    f32x4 accA[4], accB[4];
    #pragma unroll
    for (int nt = 0; nt < 4; ++nt) { accA[nt] = hn[nt]; accB[nt] = hn[nt]; }
    #pragma unroll
    for (int nt = 0; nt < 4; ++nt)
        accA[nt] = __builtin_amdgcn_mfma_f32_16x16x32_bf16(a0A, w1f[0][nt], accA[nt], 0, 0, 0);
    #pragma unroll
    for (int nt = 0; nt < 4; ++nt)
        accA[nt] = __builtin_amdgcn_mfma_f32_16x16x32_bf16(a1A, w1f[1][nt], accA[nt], 0, 0, 0);
    if (vB) {
        #pragma unroll
        for (int nt = 0; nt < 4; ++nt)
            accB[nt] = __builtin_amdgcn_mfma_f32_16x16x32_bf16(a0B, w1f[0][nt], accB[nt], 0, 0, 0);
        #pragma unroll
        for (int nt = 0; nt < 4; ++nt)
            accB[nt] = __builtin_amdgcn_mfma_f32_16x16x32_bf16(a1B, w1f[1][nt], accB[nt], 0, 0, 0);
    }

    // ---- relu -> bf16 -> shared LDS transpose burst ----
    #pragma unroll
    for (int nt = 0; nt < 4; ++nt) {
        unsigned p0 = cvt_pk(fmaxf(accA[nt][0], 0.f), fmaxf(accA[nt][1], 0.f));
        unsigned p1 = cvt_pk(fmaxf(accA[nt][2], 0.f), fmaxf(accA[nt][3], 0.f));
        hwA[(g * 4 + 0) * 72 + nt * 16 + l15] = (unsigned short)p0;
        hwA[(g * 4 + 1) * 72 + nt * 16 + l15] = (unsigned short)(p0 >> 16);
        hwA[(g * 4 + 2) * 72 + nt * 16 + l15] = (unsigned short)p1;
        hwA[(g * 4 + 3) * 72 + nt * 16 + l15] = (unsigned short)(p1 >> 16);
    }
    if (vB) {
        #pragma unroll
        for (int nt = 0; nt < 4; ++nt) {
            unsigned p0 = cvt_pk(fmaxf(accB[nt][0], 0.f), fmaxf(accB[nt][1], 0.f));
            unsigned p1 = cvt_pk(fmaxf(accB[nt][2], 0.f), fmaxf(accB[nt][3], 0.f));
            hwB[(g * 4 + 0) * 72 + nt * 16 + l15] = (unsigned short)p0;
            hwB[(g * 4 + 1) * 72 + nt * 16 + l15] = (unsigned short)(p0 >> 16);
            hwB[(g * 4 + 2) * 72 + nt * 16 + l15] = (unsigned short)p1;
            hwB[(g * 4 + 3) * 72 + nt * 16 + l15] = (unsigned short)(p1 >> 16);
        }
    }
    bf16x8 h0A = *(const bf16x8*)&hwA[l15 * 72 + g8];
    bf16x8 h1A = *(const bf16x8*)&hwA[l15 * 72 + 32 + g8];

    // ---- layer 2 SWAPPED (col = neighbor = l15), both tiles ----
    f32x4 c2A[4], c2B[4];
    #pragma unroll
    for (int nt = 0; nt < 4; ++nt) c2A[nt] = b2r[nt];
    #pragma unroll
    for (int nt = 0; nt < 4; ++nt)
        c2A[nt] = __builtin_amdgcn_mfma_f32_16x16x32_bf16(w2f[0][nt], h0A, c2A[nt], 0, 0, 0);
    #pragma unroll
    for (int nt = 0; nt < 4; ++nt)
        c2A[nt] = __builtin_amdgcn_mfma_f32_16x16x32_bf16(w2f[1][nt], h1A, c2A[nt], 0, 0, 0);
    if (vB) {
        bf16x8 h0B = *(const bf16x8*)&hwB[l15 * 72 + g8];
        bf16x8 h1B = *(const bf16x8*)&hwB[l15 * 72 + 32 + g8];
        #pragma unroll
        for (int nt = 0; nt < 4; ++nt) c2B[nt] = b2r[nt];
        #pragma unroll
        for (int nt = 0; nt < 4; ++nt)
            c2B[nt] = __builtin_amdgcn_mfma_f32_16x16x32_bf16(w2f[0][nt], h0B, c2B[nt], 0, 0, 0);
        #pragma unroll
        for (int nt = 0; nt < 4; ++nt)
            c2B[nt] = __builtin_amdgcn_mfma_f32_16x16x32_bf16(w2f[1][nt], h1B, c2B[nt], 0, 0, 0);
    }

    // ---- layer 3 logits, both tiles ----
    float lsA = 0.f, lsB = 0.f;
    #pragma unroll
    for (int nt = 0; nt < 4; ++nt) {
        lsA = fmaf(fmaxf(c2A[nt][0], 0.f), w3r[nt][0], lsA);
        lsA = fmaf(fmaxf(c2A[nt][1], 0.f), w3r[nt][1], lsA);
        lsA = fmaf(fmaxf(c2A[nt][2], 0.f), w3r[nt][2], lsA);
        lsA = fmaf(fmaxf(c2A[nt][3], 0.f), w3r[nt][3], lsA);
    }
    lsA += __shfl_xor(lsA, 16);
    lsA += __shfl_xor(lsA, 32);
    if (vB) {
        #pragma unroll
        for (int nt = 0; nt < 4; ++nt) {
            lsB = fmaf(fmaxf(c2B[nt][0], 0.f), w3r[nt][0], lsB);
            lsB = fmaf(fmaxf(c2B[nt][1], 0.f), w3r[nt][1], lsB);
            lsB = fmaf(fmaxf(c2B[nt][2], 0.f), w3r[nt][2], lsB);
            lsB = fmaf(fmaxf(c2B[nt][3], 0.f), w3r[nt][3], lsB);
        }
        lsB += __shfl_xor(lsB, 16);
        lsB += __shfl_xor(lsB, 32);
    }

    const float lgvA = (t0 * 16 + l15 < len) ? lsA : -INFINITY;
    const float lgvB = vB ? (((t0 + 1) * 16 + l15 < len) ? lsB : -INFINITY) : -INFINITY;

    // ---- ONE softmax step per pair ----
    float pm = fmaxf(lgvA, lgvB);
    pm = fmaxf(pm, __shfl_xor(pm, 1));
    pm = fmaxf(pm, __shfl_xor(pm, 2));
    pm = fmaxf(pm, __shfl_xor(pm, 4));
    pm = fmaxf(pm, __shfl_xor(pm, 8));
    if (pm > m) {                          // wave-uniform branch
        const float sc = __expf(m - pm);   // first pair: exp(-inf)=0
        ssum *= sc;
        #pragma unroll
        for (int i = 0; i < 16; ++i) accW[i] *= sc;
        m = pm;
    }
    const float erA = __expf(lgvA - m);
    ssum += erA;
    #pragma unroll
    for (int i = 0; i < 8; ++i) {
        accW[i]     = fmaf(erA, bf2f(a0A[i]), accW[i]);
        accW[8 + i] = fmaf(erA, bf2f(a1A[i]), accW[8 + i]);
    }
    if (vB) {
        const float erB = __expf(lgvB - m);
        ssum += erB;
        #pragma unroll
        for (int i = 0; i < 8; ++i) {
            accW[i]     = fmaf(erB, bf2f(a0B[i]), accW[i]);
            accW[8 + i] = fmaf(erB, bf2f(a1B[i]), accW[8 + i]);
        }
    }
}

__device__ __forceinline__ void process_elem(
    const float* __restrict__ i_table, float* __restrict__ out,
    int b, int len, const int (&idx)[4],
    bf16x8 axu0, bf16x8 axu1,
    const bf16x8 (&w1f)[4][4], const bf16x8 (&w2f)[2][4],
    const float (&b1v)[4], const f32x4 (&b2r)[4], const f32x4 (&w3r)[4],
    unsigned short* __restrict__ hw, int l15, int g)
{
    const int g8    = g * 8;
    const int ntile = (len + 15) >> 4;

    float4 LA[4][4];
    #define ISSUE_T(t) if ((t) < ntile) { \
        const float* xp = i_table + (size_t)idx[t] * 64 + g8; \
        LA[t][0] = *(const float4*)(xp); \
        LA[t][1] = *(const float4*)(xp + 4); \
        LA[t][2] = *(const float4*)(xp + 32); \
        LA[t][3] = *(const float4*)(xp + 36); \
    }
    ISSUE_T(0)
    ISSUE_T(1)

    // ---- node half of layer 1 ----
    f32x4 hn[4];
    #pragma unroll
    for (int nt = 0; nt < 4; ++nt)
        hn[nt] = (f32x4){b1v[nt], b1v[nt], b1v[nt], b1v[nt]};
    #pragma unroll
    for (int nt = 0; nt < 4; ++nt)
        hn[nt] = __builtin_amdgcn_mfma_f32_16x16x32_bf16(axu0, w1f[2][nt], hn[nt], 0, 0, 0);
    #pragma unroll
    for (int nt = 0; nt < 4; ++nt)
        hn[nt] = __builtin_amdgcn_mfma_f32_16x16x32_bf16(axu1, w1f[3][nt], hn[nt], 0, 0, 0);

    float m = -INFINITY, ssum = 0.f;
    float accW[16];
    #pragma unroll
    for (int i = 0; i < 16; ++i) accW[i] = 0.f;

    // ---- pair 0 (tiles 0,1) ----
    {
        bf16x8 a0A = cvt8f(LA[0][0], LA[0][1]);
        bf16x8 a1A = cvt8f(LA[0][2], LA[0][3]);
        bf16x8 a0B = {0,0,0,0,0,0,0,0}, a1B = {0,0,0,0,0,0,0,0};
        if (ntile > 1) {
            a0B = cvt8f(LA[1][0], LA[1][1]);
            a1B = cvt8f(LA[1][2], LA[1][3]);
        }
        ISSUE_T(2)
        ISSUE_T(3)
        pair_compute(0, len, ntile > 1, a0A, a1A, a0B, a1B,
                     hn, w1f, w2f, b2r, w3r, hw, l15, g, m, ssum, accW);
    }
    // ---- pair 1 (tiles 2,3) ----
    if (ntile > 2) {
        bf16x8 a0A = cvt8f(LA[2][0], LA[2][1]);
        bf16x8 a1A = cvt8f(LA[2][2], LA[2][3]);
        bf16x8 a0B = {0,0,0,0,0,0,0,0}, a1B = {0,0,0,0,0,0,0,0};
        if (ntile > 3) {
            a0B = cvt8f(LA[3][0], LA[3][1]);
            a1B = cvt8f(LA[3][2], LA[3][3]);
        }
        pair_compute(2, len, ntile > 3, a0A, a1A, a0B, a1B,
                     hn, w1f, w2f, b2r, w3r, hw, l15, g, m, ssum, accW);
    }
    #undef ISSUE_T

    // ---- finalize ----
    #pragma unroll
    for (int i = 0; i < 16; ++i) {
        accW[i] += __shfl_xor(accW[i], 1);
        accW[i] += __shfl_xor(accW[i], 2);
        accW[i] += __shfl_xor(accW[i], 4);
        accW[i] += __shfl_xor(accW[i], 8);
    }
    float ss = ssum;
    ss += __shfl_xor(ss, 1);
    ss += __shfl_xor(ss, 2);
    ss += __shfl_xor(ss, 4);
    ss += __shfl_xor(ss, 8);
    const float inv = 1.f / ss;
    if (l15 == 0) {
        float4 o0 = make_float4(accW[0]  * inv, accW[1]  * inv, accW[2]  * inv, accW[3]  * inv);
        float4 o1 = make_float4(accW[4]  * inv, accW[5]  * inv, accW[6]  * inv, accW[7]  * inv);
        float4 o2 = make_float4(accW[8]  * inv, accW[9]  * inv, accW[10] * inv, accW[11] * inv);
        float4 o3 = make_float4(accW[12] * inv, accW[13] * inv, accW[14] * inv, accW[15] * inv);
        *(float4*)(out + b * 64 +      g8)     = o0;
        *(float4*)(out + b * 64 +      g8 + 4) = o1;
        *(float4*)(out + b * 64 + 32 + g8)     = o2;
        *(float4*)(out + b * 64 + 32 + g8 + 4) = o3;
    }
}

__global__ __launch_bounds__(256, 2) void graphrec_k(
    const float* __restrict__ u_table, const float* __restrict__ i_table,
    const float* __restrict__ W1, const float* __restrict__ b1,
    const float* __restrict__ W2, const float* __restrict__ b2,
    const float* __restrict__ W3, const float* __restrict__ b3,
    const int* __restrict__ nodes, const int* __restrict__ neighbors,
    const int* __restrict__ lengths, float* __restrict__ out)
{
    __shared__ __attribute__((aligned(16))) short WL[24][64][8];                // 24.5 KB
    __shared__ __attribute__((aligned(16))) unsigned short Hs[4][2 * 16 * 72];  // 18.4 KB

    const int tid  = threadIdx.x;
    const int w    = tid >> 6, lane = tid & 63;
    const int l15  = lane & 15, g = lane >> 4, g8 = g * 8;

    // ---- stage weights as frags (B-frag for M, A-frag for M^T) ----
    for (int f = w; f < 24; f += 4) {
        const float* Ws = (f < 16) ? W1 : W2;
        const int    fi = (f < 16) ? f : f - 16;
        const int    ks = fi >> 2, nt = fi & 3;
        const float* p  = Ws + (ks * 32 + g8) * 64 + nt * 16 + l15;
        bfu r;
        r.u[0] = cvt_pk(p[0 * 64], p[1 * 64]);
        r.u[1] = cvt_pk(p[2 * 64], p[3 * 64]);
        r.u[2] = cvt_pk(p[4 * 64], p[5 * 64]);
        r.u[3] = cvt_pk(p[6 * 64], p[7 * 64]);
        *(bf16x8*)&WL[f][lane][0] = r.v;
    }
    __syncthreads();

    bf16x8 w1f[4][4], w2f[2][4];
    #pragma unroll
    for (int ks = 0; ks < 4; ++ks)
        #pragma unroll
        for (int nt = 0; nt < 4; ++nt)
            w1f[ks][nt] = *(const bf16x8*)&WL[ks * 4 + nt][lane][0];
    #pragma unroll
    for (int ks = 0; ks < 2; ++ks)
        #pragma unroll
        for (int nt = 0; nt < 4; ++nt)
            w2f[ks][nt] = *(const bf16x8*)&WL[16 + ks * 4 + nt][lane][0];

    float b1v[4];
    f32x4 b2r[4], w3r[4];
    #pragma unroll
    for (int nt = 0; nt < 4; ++nt) {
        b1v[nt] = b1[nt * 16 + l15];
        b2r[nt] = *(const f32x4*)(b2 + nt * 16 + 4 * g);
        w3r[nt] = *(const f32x4*)(W3 + nt * 16 + 4 * g);
    }
    // b3 shifts all logits equally -> softmax-invariant, skip.

    const int wid = blockIdx.x * 4 + w;
    const int b0  = wid, b1e = wid + NWAVE;

    const int len0 = lengths[b0], len1 = lengths[b1e];
    const int nd0  = nodes[b0],   nd1  = nodes[b1e];

    int idx0[4], idx1[4];
    const int nt0 = (len0 + 15) >> 4, nt1 = (len1 + 15) >> 4;
    #pragma unroll
    for (int t = 0; t < 4; ++t) {
        int r = t * 16 + l15; if (r >= len0) r = len0 - 1;
        idx0[t] = (t < nt0) ? neighbors[b0 * LMAX + r] : 0;
    }
    #pragma unroll
    for (int t = 0; t < 4; ++t) {
        int r = t * 16 + l15; if (r >= len1) r = len1 - 1;
        idx1[t] = (t < nt1) ? neighbors[b1e * LMAX + r] : 0;
    }

    const float* up0 = u_table + (size_t)nd0 * 64 + g8;
    const float* up1 = u_table + (size_t)nd1 * 64 + g8;
    float4 U00 = *(const float4*)(up0);
    float4 U01 = *(const float4*)(up0 + 4);
    float4 U02 = *(const float4*)(up0 + 32);
    float4 U03 = *(const float4*)(up0 + 36);
    float4 U10 = *(const float4*)(up1);
    float4 U11 = *(const float4*)(up1 + 4);
    float4 U12 = *(const float4*)(up1 + 32);
    float4 U13 = *(const float4*)(up1 + 36);

    process_elem(i_table, out, b0, len0, idx0,
                 cvt8f(U00, U01), cvt8f(U02, U03),
                 w1f, w2f, b1v, b2r, w3r, &Hs[w][0], l15, g);

    process_elem(i_table, out, b1e, len1, idx1,
                 cvt8f(U10, U11), cvt8f(U12, U13),
                 w1f, w2f, b1v, b2r, w3r, &Hs[w][0], l15, g);
}

extern "C" void kernel_launch(void* const* d_in, const int* in_sizes, int n_in,
                              void* d_out, int out_size, void* d_ws, size_t ws_size,
                              hipStream_t stream) {
    const float* u_table   = (const float*)d_in[0];
    const float* i_table   = (const float*)d_in[1];
    const float* W1        = (const float*)d_in[2];
    const float* b1        = (const float*)d_in[3];
    const float* W2        = (const float*)d_in[4];
    const float* b2        = (const float*)d_in[5];
    const float* W3        = (const float*)d_in[6];
    const float* b3        = (const float*)d_in[7];
    const int*   nodes     = (const int*)d_in[8];
    const int*   neighbors = (const int*)d_in[9];
    const int*   lengths   = (const int*)d_in[10];
    float* out = (float*)d_out;

    graphrec_k<<<dim3(NWAVE / 4), dim3(256), 0, stream>>>(
        u_table, i_table, W1, b1, W2, b2, W3, b3, nodes, neighbors, lengths, out);
}

// Round 16
// 23.144 us; speedup vs baseline: 1.3311x; 1.1510x over previous
//
#include <hip/hip_runtime.h>
#include <math.h>

#define LMAX  50
#define NWAVE 2048     // 512 blocks x 4 waves; each wave: elements wid, wid+2048

typedef short bf16x8 __attribute__((ext_vector_type(8)));
typedef float f32x4  __attribute__((ext_vector_type(4)));
union bfu { bf16x8 v; unsigned u[4]; };

__device__ __forceinline__ unsigned cvt_pk(float lo, float hi) {
    unsigned r;
    asm("v_cvt_pk_bf16_f32 %0, %1, %2" : "=v"(r) : "v"(lo), "v"(hi));
    return r;
}
__device__ __forceinline__ bf16x8 cvt8f(float4 a, float4 b) {
    bfu r;
    r.u[0] = cvt_pk(a.x, a.y); r.u[1] = cvt_pk(a.z, a.w);
    r.u[2] = cvt_pk(b.x, b.y); r.u[3] = cvt_pk(b.z, b.w);
    return r.v;
}
__device__ __forceinline__ float bf2f(short s) {
    union { unsigned u; float f; } v; v.u = ((unsigned)(unsigned short)s) << 16;
    return v.f;
}

// One tile: layer1 -> LDS transpose -> swapped layer2 -> per-lane logit.
// NO softmax state in the loop (deferred). Returns lgv for this lane's row.
__device__ __forceinline__ float tile_logit(
    int t, int len, bf16x8 a0, bf16x8 a1,
    const f32x4 (&hn)[4],
    const bf16x8 (&w1f)[4][4], const bf16x8 (&w2f)[2][4],
    const f32x4 (&b2r)[4], const f32x4 (&w3r)[4],
    unsigned short* __restrict__ hw, int l15, int g)
{
    const int g8 = g * 8;

    // ---- layer 1 (neighbor half), K=64 on top of hn ----
    f32x4 acc[4];
    #pragma unroll
    for (int nt = 0; nt < 4; ++nt) acc[nt] = hn[nt];
    #pragma unroll
    for (int nt = 0; nt < 4; ++nt)
        acc[nt] = __builtin_amdgcn_mfma_f32_16x16x32_bf16(a0, w1f[0][nt], acc[nt], 0, 0, 0);
    #pragma unroll
    for (int nt = 0; nt < 4; ++nt)
        acc[nt] = __builtin_amdgcn_mfma_f32_16x16x32_bf16(a1, w1f[1][nt], acc[nt], 0, 0, 0);

    // relu -> bf16 -> per-wave LDS transpose (C: row g*4+reg, col nt*16+l15)
    #pragma unroll
    for (int nt = 0; nt < 4; ++nt) {
        unsigned p0 = cvt_pk(fmaxf(acc[nt][0], 0.f), fmaxf(acc[nt][1], 0.f));
        unsigned p1 = cvt_pk(fmaxf(acc[nt][2], 0.f), fmaxf(acc[nt][3], 0.f));
        hw[(g * 4 + 0) * 72 + nt * 16 + l15] = (unsigned short)p0;
        hw[(g * 4 + 1) * 72 + nt * 16 + l15] = (unsigned short)(p0 >> 16);
        hw[(g * 4 + 2) * 72 + nt * 16 + l15] = (unsigned short)p1;
        hw[(g * 4 + 3) * 72 + nt * 16 + l15] = (unsigned short)(p1 >> 16);
    }
    bf16x8 h0 = *(const bf16x8*)&hw[l15 * 72 + g8];        // H1[nbr=l15][n1=g8+i]
    bf16x8 h1 = *(const bf16x8*)&hw[l15 * 72 + 32 + g8];

    // ---- layer 2 SWAPPED: D2 = W2^T @ H1^T (col = neighbor = l15) ----
    f32x4 c2[4];
    #pragma unroll
    for (int nt = 0; nt < 4; ++nt) c2[nt] = b2r[nt];
    #pragma unroll
    for (int nt = 0; nt < 4; ++nt)
        c2[nt] = __builtin_amdgcn_mfma_f32_16x16x32_bf16(w2f[0][nt], h0, c2[nt], 0, 0, 0);
    #pragma unroll
    for (int nt = 0; nt < 4; ++nt)
        c2[nt] = __builtin_amdgcn_mfma_f32_16x16x32_bf16(w2f[1][nt], h1, c2[nt], 0, 0, 0);

    // ---- layer 3: per-lane VALU sum over n2, then reduce over g ----
    float ls = 0.f;
    #pragma unroll
    for (int nt = 0; nt < 4; ++nt) {
        ls = fmaf(fmaxf(c2[nt][0], 0.f), w3r[nt][0], ls);
        ls = fmaf(fmaxf(c2[nt][1], 0.f), w3r[nt][1], ls);
        ls = fmaf(fmaxf(c2[nt][2], 0.f), w3r[nt][2], ls);
        ls = fmaf(fmaxf(c2[nt][3], 0.f), w3r[nt][3], ls);
    }
    ls += __shfl_xor(ls, 16);
    ls += __shfl_xor(ls, 32);              // logit[nbr=l15], replicated over g

    return (t * 16 + l15 < len) ? ls : -INFINITY;
}

__device__ __forceinline__ void process_elem(
    const float* __restrict__ i_table, float* __restrict__ out,
    int b, int len, const int (&idx)[4],
    bf16x8 axu0, bf16x8 axu1,
    const bf16x8 (&w1f)[4][4], const bf16x8 (&w2f)[2][4],
    const float (&b1v)[4], const f32x4 (&b2r)[4], const f32x4 (&w3r)[4],
    unsigned short* __restrict__ hw, int l15, int g)
{
    const int g8    = g * 8;
    const int ntile = (len + 15) >> 4;

    float4 LA[2][4];   // 2-deep rolling gather buffers (static indexing only)
    #define ISSUE_T(t) if ((t) < ntile) { \
        const float* xp = i_table + (size_t)idx[t] * 64 + g8; \
        LA[(t) & 1][0] = *(const float4*)(xp); \
        LA[(t) & 1][1] = *(const float4*)(xp + 4); \
        LA[(t) & 1][2] = *(const float4*)(xp + 32); \
        LA[(t) & 1][3] = *(const float4*)(xp + 36); \
    }
    ISSUE_T(0)
    ISSUE_T(1)

    // ---- node half of layer 1 ----
    f32x4 hn[4];
    #pragma unroll
    for (int nt = 0; nt < 4; ++nt)
        hn[nt] = (f32x4){b1v[nt], b1v[nt], b1v[nt], b1v[nt]};
    #pragma unroll
    for (int nt = 0; nt < 4; ++nt)
        hn[nt] = __builtin_amdgcn_mfma_f32_16x16x32_bf16(axu0, w1f[2][nt], hn[nt], 0, 0, 0);
    #pragma unroll
    for (int nt = 0; nt < 4; ++nt)
        hn[nt] = __builtin_amdgcn_mfma_f32_16x16x32_bf16(axu1, w1f[3][nt], hn[nt], 0, 0, 0);

    // ---- tile loop: logits + per-lane running max ONLY (softmax deferred).
    //      A-fragments retained (statically named, rule #20). ----
    const bf16x8 z8 = {0,0,0,0,0,0,0,0};
    bf16x8 a0_0 = z8, a1_0 = z8, a0_1 = z8, a1_1 = z8;
    bf16x8 a0_2 = z8, a1_2 = z8, a0_3 = z8, a1_3 = z8;
    float lg0 = -INFINITY, lg1 = -INFINITY, lg2 = -INFINITY, lg3 = -INFINITY;
    float mx = -INFINITY;

    {
        a0_0 = cvt8f(LA[0][0], LA[0][1]);
        a1_0 = cvt8f(LA[0][2], LA[0][3]);
        ISSUE_T(2)
        lg0 = tile_logit(0, len, a0_0, a1_0, hn, w1f, w2f, b2r, w3r, hw, l15, g);
        mx = lg0;
    }
    if (ntile > 1) {
        a0_1 = cvt8f(LA[1][0], LA[1][1]);
        a1_1 = cvt8f(LA[1][2], LA[1][3]);
        ISSUE_T(3)
        lg1 = tile_logit(1, len, a0_1, a1_1, hn, w1f, w2f, b2r, w3r, hw, l15, g);
        mx = fmaxf(mx, lg1);
    }
    if (ntile > 2) {
        a0_2 = cvt8f(LA[0][0], LA[0][1]);
        a1_2 = cvt8f(LA[0][2], LA[0][3]);
        lg2 = tile_logit(2, len, a0_2, a1_2, hn, w1f, w2f, b2r, w3r, hw, l15, g);
        mx = fmaxf(mx, lg2);
    }
    if (ntile > 3) {
        a0_3 = cvt8f(LA[1][0], LA[1][1]);
        a1_3 = cvt8f(LA[1][2], LA[1][3]);
        lg3 = tile_logit(3, len, a0_3, a1_3, hn, w1f, w2f, b2r, w3r, hw, l15, g);
        mx = fmaxf(mx, lg3);
    }
    #undef ISSUE_T

    // ---- deferred softmax: ONE max reduce, then exp + weighted accumulate ----
    mx = fmaxf(mx, __shfl_xor(mx, 1));
    mx = fmaxf(mx, __shfl_xor(mx, 2));
    mx = fmaxf(mx, __shfl_xor(mx, 4));
    mx = fmaxf(mx, __shfl_xor(mx, 8));     // global max m (replicated over g)

    float accW[16];
    #pragma unroll
    for (int i = 0; i < 16; ++i) accW[i] = 0.f;
    float ssum = 0.f;

    {   // tile 0 (always valid)
        const float er = __expf(lg0 - mx);     // masked rows: exp(-inf)=0
        ssum += er;
        #pragma unroll
        for (int i = 0; i < 8; ++i) {
            accW[i]     = fmaf(er, bf2f(a0_0[i]), accW[i]);
            accW[8 + i] = fmaf(er, bf2f(a1_0[i]), accW[8 + i]);
        }
    }
    if (ntile > 1) {
        const float er = __expf(lg1 - mx);
        ssum += er;
        #pragma unroll
        for (int i = 0; i < 8; ++i) {
            accW[i]     = fmaf(er, bf2f(a0_1[i]), accW[i]);
            accW[8 + i] = fmaf(er, bf2f(a1_1[i]), accW[8 + i]);
        }
    }
    if (ntile > 2) {
        const float er = __expf(lg2 - mx);
        ssum += er;
        #pragma unroll
        for (int i = 0; i < 8; ++i) {
            accW[i]     = fmaf(er, bf2f(a0_2[i]), accW[i]);
            accW[8 + i] = fmaf(er, bf2f(a1_2[i]), accW[8 + i]);
        }
    }
    if (ntile > 3) {
        const float er = __expf(lg3 - mx);
        ssum += er;
        #pragma unroll
        for (int i = 0; i < 8; ++i) {
            accW[i]     = fmaf(er, bf2f(a0_3[i]), accW[i]);
            accW[8 + i] = fmaf(er, bf2f(a1_3[i]), accW[8 + i]);
        }
    }

    // ---- finalize: reduce over the 16 tile rows (l15), write 64 dims ----
    #pragma unroll
    for (int i = 0; i < 16; ++i) {
        accW[i] += __shfl_xor(accW[i], 1);
        accW[i] += __shfl_xor(accW[i], 2);
        accW[i] += __shfl_xor(accW[i], 4);
        accW[i] += __shfl_xor(accW[i], 8);
    }
    float ss = ssum;
    ss += __shfl_xor(ss, 1);
    ss += __shfl_xor(ss, 2);
    ss += __shfl_xor(ss, 4);
    ss += __shfl_xor(ss, 8);
    const float inv = 1.f / ss;
    if (l15 == 0) {
        float4 o0 = make_float4(accW[0]  * inv, accW[1]  * inv, accW[2]  * inv, accW[3]  * inv);
        float4 o1 = make_float4(accW[4]  * inv, accW[5]  * inv, accW[6]  * inv, accW[7]  * inv);
        float4 o2 = make_float4(accW[8]  * inv, accW[9]  * inv, accW[10] * inv, accW[11] * inv);
        float4 o3 = make_float4(accW[12] * inv, accW[13] * inv, accW[14] * inv, accW[15] * inv);
        *(float4*)(out + b * 64 +      g8)     = o0;
        *(float4*)(out + b * 64 +      g8 + 4) = o1;
        *(float4*)(out + b * 64 + 32 + g8)     = o2;
        *(float4*)(out + b * 64 + 32 + g8 + 4) = o3;
    }
}

__global__ __launch_bounds__(256, 2) void graphrec_k(
    const float* __restrict__ u_table, const float* __restrict__ i_table,
    const float* __restrict__ W1, const float* __restrict__ b1,
    const float* __restrict__ W2, const float* __restrict__ b2,
    const float* __restrict__ W3, const float* __restrict__ b3,
    const int* __restrict__ nodes, const int* __restrict__ neighbors,
    const int* __restrict__ lengths, float* __restrict__ out)
{
    __shared__ __attribute__((aligned(16))) short WL[24][64][8];            // 24.5 KB
    __shared__ __attribute__((aligned(16))) unsigned short Hs[4][16 * 72];  //  9.2 KB

    const int tid  = threadIdx.x;
    const int w    = tid >> 6, lane = tid & 63;
    const int l15  = lane & 15, g = lane >> 4, g8 = g * 8;

    // ---- stage weights as frags (B-frag for M, A-frag for M^T) ----
    for (int f = w; f < 24; f += 4) {
        const float* Ws = (f < 16) ? W1 : W2;
        const int    fi = (f < 16) ? f : f - 16;
        const int    ks = fi >> 2, nt = fi & 3;
        const float* p  = Ws + (ks * 32 + g8) * 64 + nt * 16 + l15;
        bfu r;
        r.u[0] = cvt_pk(p[0 * 64], p[1 * 64]);
        r.u[1] = cvt_pk(p[2 * 64], p[3 * 64]);
        r.u[2] = cvt_pk(p[4 * 64], p[5 * 64]);
        r.u[3] = cvt_pk(p[6 * 64], p[7 * 64]);
        *(bf16x8*)&WL[f][lane][0] = r.v;
    }
    __syncthreads();

    bf16x8 w1f[4][4], w2f[2][4];
    #pragma unroll
    for (int ks = 0; ks < 4; ++ks)
        #pragma unroll
        for (int nt = 0; nt < 4; ++nt)
            w1f[ks][nt] = *(const bf16x8*)&WL[ks * 4 + nt][lane][0];
    #pragma unroll
    for (int ks = 0; ks < 2; ++ks)
        #pragma unroll
        for (int nt = 0; nt < 4; ++nt)
            w2f[ks][nt] = *(const bf16x8*)&WL[16 + ks * 4 + nt][lane][0];

    float b1v[4];
    f32x4 b2r[4], w3r[4];
    #pragma unroll
    for (int nt = 0; nt < 4; ++nt) {
        b1v[nt] = b1[nt * 16 + l15];
        b2r[nt] = *(const f32x4*)(b2 + nt * 16 + 4 * g);
        w3r[nt] = *(const f32x4*)(W3 + nt * 16 + 4 * g);
    }
    // b3 shifts all logits equally -> softmax-invariant, skip.

    const int wid = blockIdx.x * 4 + w;
    const int b0  = wid, b1e = wid + NWAVE;

    const int len0 = lengths[b0], len1 = lengths[b1e];
    const int nd0  = nodes[b0],   nd1  = nodes[b1e];

    int idx0[4], idx1[4];
    const int nt0 = (len0 + 15) >> 4, nt1 = (len1 + 15) >> 4;
    #pragma unroll
    for (int t = 0; t < 4; ++t) {
        int r = t * 16 + l15; if (r >= len0) r = len0 - 1;
        idx0[t] = (t < nt0) ? neighbors[b0 * LMAX + r] : 0;
    }
    #pragma unroll
    for (int t = 0; t < 4; ++t) {
        int r = t * 16 + l15; if (r >= len1) r = len1 - 1;
        idx1[t] = (t < nt1) ? neighbors[b1e * LMAX + r] : 0;
    }

    const float* up0 = u_table + (size_t)nd0 * 64 + g8;
    const float* up1 = u_table + (size_t)nd1 * 64 + g8;
    float4 U00 = *(const float4*)(up0);
    float4 U01 = *(const float4*)(up0 + 4);
    float4 U02 = *(const float4*)(up0 + 32);
    float4 U03 = *(const float4*)(up0 + 36);
    float4 U10 = *(const float4*)(up1);      // stays f32 until elem1 (in flight)
    float4 U11 = *(const float4*)(up1 + 4);
    float4 U12 = *(const float4*)(up1 + 32);
    float4 U13 = *(const float4*)(up1 + 36);

    process_elem(i_table, out, b0, len0, idx0,
                 cvt8f(U00, U01), cvt8f(U02, U03),
                 w1f, w2f, b1v, b2r, w3r, &Hs[w][0], l15, g);

    process_elem(i_table, out, b1e, len1, idx1,
                 cvt8f(U10, U11), cvt8f(U12, U13),
                 w1f, w2f, b1v, b2r, w3r, &Hs[w][0], l15, g);
}

extern "C" void kernel_launch(void* const* d_in, const int* in_sizes, int n_in,
                              void* d_out, int out_size, void* d_ws, size_t ws_size,
                              hipStream_t stream) {
    const float* u_table   = (const float*)d_in[0];
    const float* i_table   = (const float*)d_in[1];
    const float* W1        = (const float*)d_in[2];
    const float* b1        = (const float*)d_in[3];
    const float* W2        = (const float*)d_in[4];
    const float* b2        = (const float*)d_in[5];
    const float* W3        = (const float*)d_in[6];
    const float* b3        = (const float*)d_in[7];
    const int*   nodes     = (const int*)d_in[8];
    const int*   neighbors = (const int*)d_in[9];
    const int*   lengths   = (const int*)d_in[10];
    float* out = (float*)d_out;

    graphrec_k<<<dim3(NWAVE / 4), dim3(256), 0, stream>>>(
        u_table, i_table, W1, b1, W2, b2, W3, b3, nodes, neighbors, lengths, out);
}

// Round 17
// 22.359 us; speedup vs baseline: 1.3779x; 1.0351x over previous
//
#include <hip/hip_runtime.h>
#include <math.h>

#define LMAX  50
#define NWAVE 2048     // 512 blocks x 4 waves; each wave: elements wid, wid+2048

typedef short bf16x8 __attribute__((ext_vector_type(8)));
typedef float f32x4  __attribute__((ext_vector_type(4)));
union bfu { bf16x8 v; unsigned u[4]; };

// packed f32 pair -> 2x bf16 (RNE), single VALU instr
__device__ __forceinline__ unsigned cvt_pk(float lo, float hi) {
    unsigned r;
    asm("v_cvt_pk_bf16_f32 %0, %1, %2" : "=v"(r) : "v"(lo), "v"(hi));
    return r;
}
__device__ __forceinline__ bf16x8 cvt8f(float4 a, float4 b) {
    bfu r;
    r.u[0] = cvt_pk(a.x, a.y); r.u[1] = cvt_pk(a.z, a.w);
    r.u[2] = cvt_pk(b.x, b.y); r.u[3] = cvt_pk(b.z, b.w);
    return r.v;
}
__device__ __forceinline__ float bf2f(short s) {
    union { unsigned u; float f; } v; v.u = ((unsigned)(unsigned short)s) << 16;
    return v.f;
}

// One batch element. Layer 1: D = X@W1 (rows=neighbors). Transpose via LDS.
// Layer 2 SWAPPED: D2 = W2^T @ H1^T -> col = neighbor = l15, row = n2.
// Logit = per-lane VALU sum over n2 + 2 shuffles; er lands in the right lane
// for accW (no Ls broadcast). ssum is a per-lane partial (reduced at the end).
__device__ __forceinline__ void process_elem(
    const float* __restrict__ i_table, float* __restrict__ out,
    int b, int len, const int (&idx)[6],
    bf16x8 axu0, bf16x8 axu1,
    const bf16x8 (&w1f)[4][4], const bf16x8 (&w2f)[2][4],
    const float (&b1v)[4], const f32x4 (&b2r)[4], const f32x4 (&w3r)[4],
    unsigned short* __restrict__ hw,
    int l15, int g)
{
    const int g8    = g * 8;
    const int ntile = (len + 15) >> 4;

    float4 LA[2][4];   // 2-deep rolling gather buffers (static indexing only)
    #define ISSUE(t) if ((t) < ntile) { \
        const float* xp = i_table + (size_t)idx[t] * 64 + g8; \
        LA[(t) & 1][0] = *(const float4*)(xp); \
        LA[(t) & 1][1] = *(const float4*)(xp + 4); \
        LA[(t) & 1][2] = *(const float4*)(xp + 32); \
        LA[(t) & 1][3] = *(const float4*)(xp + 36); \
    }
    ISSUE(0)
    ISSUE(1)

    // ---- node half of layer 1 (identical for all rows): hn = b1 + xu@W1n ----
    f32x4 hn[4];
    #pragma unroll
    for (int nt = 0; nt < 4; ++nt)
        hn[nt] = (f32x4){b1v[nt], b1v[nt], b1v[nt], b1v[nt]};
    #pragma unroll
    for (int nt = 0; nt < 4; ++nt)
        hn[nt] = __builtin_amdgcn_mfma_f32_16x16x32_bf16(axu0, w1f[2][nt], hn[nt], 0, 0, 0);
    #pragma unroll
    for (int nt = 0; nt < 4; ++nt)
        hn[nt] = __builtin_amdgcn_mfma_f32_16x16x32_bf16(axu1, w1f[3][nt], hn[nt], 0, 0, 0);

    float m = -INFINITY, ssum = 0.f;   // ssum: per-lane partial (row l15)
    float accW[16];
    #pragma unroll
    for (int i = 0; i < 16; ++i) accW[i] = 0.f;

    #pragma unroll
    for (int t = 0; t < 4; ++t) {
        if (t < ntile) {
            bf16x8 a0 = cvt8f(LA[t & 1][0], LA[t & 1][1]);
            bf16x8 a1 = cvt8f(LA[t & 1][2], LA[t & 1][3]);
            if (t + 2 < 4) ISSUE(t + 2)     // folds at compile time

            // ---- layer 1 (neighbor half), K=64 on top of hn ----
            f32x4 acc[4];
            #pragma unroll
            for (int nt = 0; nt < 4; ++nt) acc[nt] = hn[nt];
            #pragma unroll
            for (int nt = 0; nt < 4; ++nt)
                acc[nt] = __builtin_amdgcn_mfma_f32_16x16x32_bf16(a0, w1f[0][nt], acc[nt], 0, 0, 0);
            #pragma unroll
            for (int nt = 0; nt < 4; ++nt)
                acc[nt] = __builtin_amdgcn_mfma_f32_16x16x32_bf16(a1, w1f[1][nt], acc[nt], 0, 0, 0);

            // relu -> bf16 -> per-wave LDS transpose (C: row g*4+reg, col nt*16+l15)
            #pragma unroll
            for (int nt = 0; nt < 4; ++nt) {
                unsigned p0 = cvt_pk(fmaxf(acc[nt][0], 0.f), fmaxf(acc[nt][1], 0.f));
                unsigned p1 = cvt_pk(fmaxf(acc[nt][2], 0.f), fmaxf(acc[nt][3], 0.f));
                hw[(g * 4 + 0) * 72 + nt * 16 + l15] = (unsigned short)p0;
                hw[(g * 4 + 1) * 72 + nt * 16 + l15] = (unsigned short)(p0 >> 16);
                hw[(g * 4 + 2) * 72 + nt * 16 + l15] = (unsigned short)p1;
                hw[(g * 4 + 3) * 72 + nt * 16 + l15] = (unsigned short)(p1 >> 16);
            }
            bf16x8 h0 = *(const bf16x8*)&hw[l15 * 72 + g8];        // H1[nbr=l15][n1=g8+i]
            bf16x8 h1 = *(const bf16x8*)&hw[l15 * 72 + 32 + g8];

            // ---- layer 2 SWAPPED: D2 = W2^T @ H1^T  (col = neighbor = l15,
            //      row = n2 = nt*16 + g*4 + reg).  Same WL frags serve as A. ----
            f32x4 c2[4];
            #pragma unroll
            for (int nt = 0; nt < 4; ++nt) c2[nt] = b2r[nt];
            #pragma unroll
            for (int nt = 0; nt < 4; ++nt)
                c2[nt] = __builtin_amdgcn_mfma_f32_16x16x32_bf16(w2f[0][nt], h0, c2[nt], 0, 0, 0);
            #pragma unroll
            for (int nt = 0; nt < 4; ++nt)
                c2[nt] = __builtin_amdgcn_mfma_f32_16x16x32_bf16(w2f[1][nt], h1, c2[nt], 0, 0, 0);

            // ---- layer 3: per-lane VALU sum over n2, then reduce over g ----
            float ls = 0.f;
            #pragma unroll
            for (int nt = 0; nt < 4; ++nt) {
                ls = fmaf(fmaxf(c2[nt][0], 0.f), w3r[nt][0], ls);
                ls = fmaf(fmaxf(c2[nt][1], 0.f), w3r[nt][1], ls);
                ls = fmaf(fmaxf(c2[nt][2], 0.f), w3r[nt][2], ls);
                ls = fmaf(fmaxf(c2[nt][3], 0.f), w3r[nt][3], ls);
            }
            ls += __shfl_xor(ls, 16);
            ls += __shfl_xor(ls, 32);          // logit[nbr=l15], replicated over g

            const int rabs = t * 16 + l15;
            const float lgv = (rabs < len) ? ls : -INFINITY;   // per-lane mask

            // tile max over rows (l15); result uniform (lgv replicated over g)
            float tm = fmaxf(lgv, __shfl_xor(lgv, 1));
            tm = fmaxf(tm, __shfl_xor(tm, 2));
            tm = fmaxf(tm, __shfl_xor(tm, 4));
            tm = fmaxf(tm, __shfl_xor(tm, 8));
            if (tm > m) {                      // wave-uniform branch
                const float sc = __expf(m - tm);   // first tile: exp(-inf)=0
                ssum *= sc;
                #pragma unroll
                for (int i = 0; i < 16; ++i) accW[i] *= sc;
                m = tm;
            }
            const float er = __expf(lgv - m);  // this lane's row weight (0 if masked)
            ssum += er;

            // weighted-x partials straight from the A-fragments (er in-lane!)
            #pragma unroll
            for (int i = 0; i < 8; ++i) {
                accW[i]     = fmaf(er, bf2f(a0[i]), accW[i]);
                accW[8 + i] = fmaf(er, bf2f(a1[i]), accW[8 + i]);
            }
        }
    }
    #undef ISSUE

    // ---- finalize: reduce over the 16 rows (l15), write 64 dims ----
    #pragma unroll
    for (int i = 0; i < 16; ++i) {
        accW[i] += __shfl_xor(accW[i], 1);
        accW[i] += __shfl_xor(accW[i], 2);
        accW[i] += __shfl_xor(accW[i], 4);
        accW[i] += __shfl_xor(accW[i], 8);
    }
    float ss = ssum;
    ss += __shfl_xor(ss, 1);
    ss += __shfl_xor(ss, 2);
    ss += __shfl_xor(ss, 4);
    ss += __shfl_xor(ss, 8);                   // Σ over rows; replicated over g
    const float inv = 1.f / ss;
    if (l15 == 0) {
        float4 o0 = make_float4(accW[0]  * inv, accW[1]  * inv, accW[2]  * inv, accW[3]  * inv);
        float4 o1 = make_float4(accW[4]  * inv, accW[5]  * inv, accW[6]  * inv, accW[7]  * inv);
        float4 o2 = make_float4(accW[8]  * inv, accW[9]  * inv, accW[10] * inv, accW[11] * inv);
        float4 o3 = make_float4(accW[12] * inv, accW[13] * inv, accW[14] * inv, accW[15] * inv);
        *(float4*)(out + b * 64 +      g8)     = o0;
        *(float4*)(out + b * 64 +      g8 + 4) = o1;
        *(float4*)(out + b * 64 + 32 + g8)     = o2;
        *(float4*)(out + b * 64 + 32 + g8 + 4) = o3;
    }
}

__global__ __launch_bounds__(256, 2) void graphrec_k(
    const float* __restrict__ u_table, const float* __restrict__ i_table,
    const float* __restrict__ W1, const float* __restrict__ b1,
    const float* __restrict__ W2, const float* __restrict__ b2,
    const float* __restrict__ W3, const float* __restrict__ b3,
    const int* __restrict__ nodes, const int* __restrict__ neighbors,
    const int* __restrict__ lengths, float* __restrict__ out)
{
    __shared__ __attribute__((aligned(16))) short WL[24][64][8];            // 24.5 KB
    __shared__ __attribute__((aligned(16))) unsigned short Hs[4][16 * 72];  //  9.2 KB

    const int tid  = threadIdx.x;
    const int w    = tid >> 6, lane = tid & 63;
    const int l15  = lane & 15, g = lane >> 4, g8 = g * 8;

    // ---- stage weights as frags: lane(l15,g) holds M[ks*32+g8+i][nt*16+l15].
    //      Serves as B-frag for M (layer 1) and as A-frag for M^T (layer 2). ----
    for (int f = w; f < 24; f += 4) {
        const float* Ws = (f < 16) ? W1 : W2;
        const int    fi = (f < 16) ? f : f - 16;
        const int    ks = fi >> 2, nt = fi & 3;
        const float* p  = Ws + (ks * 32 + g8) * 64 + nt * 16 + l15;
        bfu r;
        r.u[0] = cvt_pk(p[0 * 64], p[1 * 64]);
        r.u[1] = cvt_pk(p[2 * 64], p[3 * 64]);
        r.u[2] = cvt_pk(p[4 * 64], p[5 * 64]);
        r.u[3] = cvt_pk(p[6 * 64], p[7 * 64]);
        *(bf16x8*)&WL[f][lane][0] = r.v;
    }
    __syncthreads();

    bf16x8 w1f[4][4], w2f[2][4];
    #pragma unroll
    for (int ks = 0; ks < 4; ++ks)
        #pragma unroll
        for (int nt = 0; nt < 4; ++nt)
            w1f[ks][nt] = *(const bf16x8*)&WL[ks * 4 + nt][lane][0];
    #pragma unroll
    for (int ks = 0; ks < 2; ++ks)
        #pragma unroll
        for (int nt = 0; nt < 4; ++nt)
            w2f[ks][nt] = *(const bf16x8*)&WL[16 + ks * 4 + nt][lane][0];

    float b1v[4];
    f32x4 b2r[4], w3r[4];
    #pragma unroll
    for (int nt = 0; nt < 4; ++nt) {
        b1v[nt] = b1[nt * 16 + l15];                           // col layout (layer 1)
        b2r[nt] = *(const f32x4*)(b2 + nt * 16 + 4 * g);       // row layout (layer 2)
        w3r[nt] = *(const f32x4*)(W3 + nt * 16 + 4 * g);       // row layout (layer 3)
    }
    // b3 shifts all logits equally -> softmax-invariant, skip.

    const int wid = blockIdx.x * 4 + w;
    const int b0  = wid, b1e = wid + NWAVE;

    // ---- both elements' prologue loads issued up-front ----
    const int len0 = lengths[b0], len1 = lengths[b1e];
    const int nd0  = nodes[b0],   nd1  = nodes[b1e];

    int idx0[6] = {0, 0, 0, 0, 0, 0}, idx1[6] = {0, 0, 0, 0, 0, 0};
    const int nt0 = (len0 + 15) >> 4, nt1 = (len1 + 15) >> 4;
    #pragma unroll
    for (int t = 0; t < 4; ++t) {
        int r = t * 16 + l15; if (r >= len0) r = len0 - 1;
        if (t < nt0) idx0[t] = neighbors[b0 * LMAX + r];
    }
    #pragma unroll
    for (int t = 0; t < 4; ++t) {
        int r = t * 16 + l15; if (r >= len1) r = len1 - 1;
        if (t < nt1) idx1[t] = neighbors[b1e * LMAX + r];
    }

    const float* up0 = u_table + (size_t)nd0 * 64 + g8;
    const float* up1 = u_table + (size_t)nd1 * 64 + g8;
    float4 U00 = *(const float4*)(up0);
    float4 U01 = *(const float4*)(up0 + 4);
    float4 U02 = *(const float4*)(up0 + 32);
    float4 U03 = *(const float4*)(up0 + 36);
    float4 U10 = *(const float4*)(up1);      // stays f32 until elem1 (in flight)
    float4 U11 = *(const float4*)(up1 + 4);
    float4 U12 = *(const float4*)(up1 + 32);
    float4 U13 = *(const float4*)(up1 + 36);

    process_elem(i_table, out, b0, len0, idx0,
                 cvt8f(U00, U01), cvt8f(U02, U03),
                 w1f, w2f, b1v, b2r, w3r, &Hs[w][0], l15, g);

    process_elem(i_table, out, b1e, len1, idx1,
                 cvt8f(U10, U11), cvt8f(U12, U13),
                 w1f, w2f, b1v, b2r, w3r, &Hs[w][0], l15, g);
}

extern "C" void kernel_launch(void* const* d_in, const int* in_sizes, int n_in,
                              void* d_out, int out_size, void* d_ws, size_t ws_size,
                              hipStream_t stream) {
    const float* u_table   = (const float*)d_in[0];
    const float* i_table   = (const float*)d_in[1];
    const float* W1        = (const float*)d_in[2];
    const float* b1        = (const float*)d_in[3];
    const float* W2        = (const float*)d_in[4];
    const float* b2        = (const float*)d_in[5];
    const float* W3        = (const float*)d_in[6];
    const float* b3        = (const float*)d_in[7];
    const int*   nodes     = (const int*)d_in[8];
    const int*   neighbors = (const int*)d_in[9];
    const int*   lengths   = (const int*)d_in[10];
    float* out = (float*)d_out;

    graphrec_k<<<dim3(NWAVE / 4), dim3(256), 0, stream>>>(
        u_table, i_table, W1, b1, W2, b2, W3, b3, nodes, neighbors, lengths, out);
}